// Round 7
// baseline (15600.826 us; speedup 1.0000x reference)
//
#include <hip/hip_runtime.h>

#define NCU     256
#define TPB     256      // 4 waves; 1 wave/SIMD -> VGPR cap 512
#define HID     2048
#define EMBD    512
#define HIN     2560
#define TSTEPS  4096
#define NCH     256

typedef unsigned long long u64;
typedef float f32x4 __attribute__((ext_vector_type(4)));

__device__ __forceinline__ float sig_(float x) { return 1.f / (1.f + __expf(-x)); }
__device__ __forceinline__ float th_(float x)  { float e = __expf(2.f * x); return 1.f - 2.f / (e + 1.f); }

__device__ __forceinline__ u64 ld_slot(const u64* p) {
    return __hip_atomic_load(p, __ATOMIC_RELAXED, __HIP_MEMORY_SCOPE_AGENT);
}

__device__ __forceinline__ float dot4(f32x4 a, f32x4 b) {
    return a.x * b.x + a.y * b.y + a.z * b.z + a.w * b.w;
}

#define PIN(v) asm volatile("" : "+v"(v))

extern "C" __global__ void __launch_bounds__(TPB, 1)
lstm_persist(const int* __restrict__ seq,
             const float* __restrict__ emb,
             const float* __restrict__ Wf, const float* __restrict__ bf,
             const float* __restrict__ Wi, const float* __restrict__ bi,
             const float* __restrict__ Wo, const float* __restrict__ bo,
             const float* __restrict__ Wc, const float* __restrict__ bc,
             const float* __restrict__ Wout, const float* __restrict__ bout,
             float* __restrict__ dout,
             u64* __restrict__ hbuf)        // [2][2048] tagged ping-pong: hi32=step, lo32=float bits
{
    const int b    = blockIdx.x;          // CU id == output char id
    const int tid  = threadIdx.x;
    const int wave = tid >> 6;
    const int lane = tid & 63;
    const int half = lane >> 5;           // two half-waves per wave
    const int s    = lane & 31;           // sublane within half
    const int R    = b * 8 + 2 * wave + half;   // global h row owned by this half-wave

    __shared__ float hs[HID];
    __shared__ float wpart[4];

    // ---- persistent weights: 320 VGPRs/thread, cap is 512 at 1 wave/SIMD ----
    // wh*[j]: cols EMBD + 4*s + 128*j + {0..3}, j=0..15  (2048 recurrent cols / 32 lanes)
    // wx*[j]: cols        4*s + 128*j + {0..3}, j=0..3   ( 512 input cols / 32 lanes)
    // wr0/1 : Wout[b][8*tid + {0..7}]
    f32x4 wh0[16], wh1[16], wh2[16], wh3[16];
    f32x4 wx0[4],  wx1[4],  wx2[4],  wx3[4];
    f32x4 wr0, wr1;
    {
        const float* b0 = Wf + (size_t)R * HIN;
        const float* b1 = Wi + (size_t)R * HIN;
        const float* b2 = Wo + (size_t)R * HIN;
        const float* b3 = Wc + (size_t)R * HIN;
        #pragma unroll
        for (int j = 0; j < 16; ++j) {
            wh0[j] = *(const f32x4*)(b0 + EMBD + 4 * s + 128 * j);
            wh1[j] = *(const f32x4*)(b1 + EMBD + 4 * s + 128 * j);
            wh2[j] = *(const f32x4*)(b2 + EMBD + 4 * s + 128 * j);
            wh3[j] = *(const f32x4*)(b3 + EMBD + 4 * s + 128 * j);
        }
        #pragma unroll
        for (int j = 0; j < 4; ++j) {
            wx0[j] = *(const f32x4*)(b0 + 4 * s + 128 * j);
            wx1[j] = *(const f32x4*)(b1 + 4 * s + 128 * j);
            wx2[j] = *(const f32x4*)(b2 + 4 * s + 128 * j);
            wx3[j] = *(const f32x4*)(b3 + 4 * s + 128 * j);
        }
        wr0 = *(const f32x4*)(Wout + (size_t)b * HID + 8 * tid);
        wr1 = *(const f32x4*)(Wout + (size_t)b * HID + 8 * tid + 4);
    }
    const float bias0 = bf[R], bias1 = bi[R], bias2 = bo[R], bias3 = bc[R];
    const float boutb = bout[b];

    float c = 0.f;
    int ch = seq[0];

    for (int t = 0; t <= TSTEPS; ++t) {
        // ---- pin weights: loop-carried, non-rematerializable ----
        #pragma unroll
        for (int j = 0; j < 16; ++j) { PIN(wh0[j]); PIN(wh1[j]); PIN(wh2[j]); PIN(wh3[j]); }
        #pragma unroll
        for (int j = 0; j < 4; ++j)  { PIN(wx0[j]); PIN(wx1[j]); PIN(wx2[j]); PIN(wx3[j]); }
        PIN(wr0); PIN(wr1);

        // ---- x-contribution first (independent of h, off the critical path) ----
        float a0 = bias0, a1 = bias1, a2 = bias2, a3 = bias3;
        if (t < TSTEPS) {
            const float* erow = emb + (size_t)ch * EMBD;
            #pragma unroll
            for (int j = 0; j < 4; ++j) {
                const f32x4 xv = *(const f32x4*)(erow + 4 * s + 128 * j);
                a0 += dot4(wx0[j], xv);
                a1 += dot4(wx1[j], xv);
                a2 += dot4(wx2[j], xv);
                a3 += dot4(wx3[j], xv);
            }
        }
        const int ch_next = (t + 1 < TSTEPS) ? seq[t + 1] : 0;

        // ---- stage h_t into LDS: poll tagged slots (store IS the arrival signal) ----
        if (t == 0) {
            #pragma unroll
            for (int k = 0; k < 8; ++k) hs[tid + 256 * k] = 0.f;
        } else {
            const u64* src = hbuf + (size_t)(t & 1) * HID;
            const unsigned tt = (unsigned)t;
            u64 v0 = ld_slot(src + tid);
            u64 v1 = ld_slot(src + tid + 256);
            u64 v2 = ld_slot(src + tid + 512);
            u64 v3 = ld_slot(src + tid + 768);
            u64 v4 = ld_slot(src + tid + 1024);
            u64 v5 = ld_slot(src + tid + 1280);
            u64 v6 = ld_slot(src + tid + 1536);
            u64 v7 = ld_slot(src + tid + 1792);
            while (((unsigned)(v0 >> 32) != tt) | ((unsigned)(v1 >> 32) != tt) |
                   ((unsigned)(v2 >> 32) != tt) | ((unsigned)(v3 >> 32) != tt) |
                   ((unsigned)(v4 >> 32) != tt) | ((unsigned)(v5 >> 32) != tt) |
                   ((unsigned)(v6 >> 32) != tt) | ((unsigned)(v7 >> 32) != tt)) {
                __builtin_amdgcn_s_sleep(1);
                v0 = ld_slot(src + tid);        v1 = ld_slot(src + tid + 256);
                v2 = ld_slot(src + tid + 512);  v3 = ld_slot(src + tid + 768);
                v4 = ld_slot(src + tid + 1024); v5 = ld_slot(src + tid + 1280);
                v6 = ld_slot(src + tid + 1536); v7 = ld_slot(src + tid + 1792);
            }
            hs[tid]        = __uint_as_float((unsigned)v0);
            hs[tid + 256]  = __uint_as_float((unsigned)v1);
            hs[tid + 512]  = __uint_as_float((unsigned)v2);
            hs[tid + 768]  = __uint_as_float((unsigned)v3);
            hs[tid + 1024] = __uint_as_float((unsigned)v4);
            hs[tid + 1280] = __uint_as_float((unsigned)v5);
            hs[tid + 1536] = __uint_as_float((unsigned)v6);
            hs[tid + 1792] = __uint_as_float((unsigned)v7);
        }
        __syncthreads();                                      // BAR B: hs ready

        // ---- gates (critical path): 16x ds_read_b128 + 256 FMA per lane ----
        if (t < TSTEPS) {
            #pragma unroll
            for (int j = 0; j < 16; ++j) {
                const f32x4 hv = *(const f32x4*)&hs[4 * s + 128 * j];  // halves broadcast
                a0 += dot4(wh0[j], hv);
                a1 += dot4(wh1[j], hv);
                a2 += dot4(wh2[j], hv);
                a3 += dot4(wh3[j], hv);
            }
            #pragma unroll
            for (int m = 16; m >= 1; m >>= 1) {   // butterfly within 32-lane half
                a0 += __shfl_xor(a0, m, 64);
                a1 += __shfl_xor(a1, m, 64);
                a2 += __shfl_xor(a2, m, 64);
                a3 += __shfl_xor(a3, m, 64);
            }
            const float f = sig_(a0);
            const float i = sig_(a1);
            const float o = sig_(a2);
            const float g = th_(a3);
            c = f * c + i * g;                    // replicated across the half-wave
            const float hn = o * th_(c);
            if (s == 0) {
                const u64 pk = ((u64)(unsigned)(t + 1) << 32) | (u64)__float_as_uint(hn);
                __hip_atomic_store(hbuf + (size_t)((t + 1) & 1) * HID + R, pk,
                                   __ATOMIC_RELAXED, __HIP_MEMORY_SCOPE_AGENT);
                if (t == TSTEPS - 1) {
                    dout[(size_t)TSTEPS * NCH + R]       = hn;   // h_last
                    dout[(size_t)TSTEPS * NCH + HID + R] = c;    // c_last
                }
            }
        }

        // ---- out[t-1][b] from staged h_t — after the h release, overlaps others' polls ----
        if (t > 0) {
            const f32x4 h0 = *(const f32x4*)&hs[8 * tid];
            const f32x4 h1 = *(const f32x4*)&hs[8 * tid + 4];
            float op = dot4(wr0, h0) + dot4(wr1, h1);
            #pragma unroll
            for (int m = 32; m >= 1; m >>= 1) op += __shfl_xor(op, m, 64);
            if (lane == 0) wpart[wave] = op;
        }
        __syncthreads();                                      // BAR C: wpart ready, hs reusable

        if (tid == 0 && t > 0) {
            dout[(size_t)(t - 1) * NCH + b] =
                wpart[0] + wpart[1] + wpart[2] + wpart[3] + boutb;
        }
        ch = ch_next;
    }
}

extern "C" void kernel_launch(void* const* d_in, const int* in_sizes, int n_in,
                              void* d_out, int out_size, void* d_ws, size_t ws_size,
                              hipStream_t stream) {
    const int*   seq  = (const int*)d_in[0];
    const float* emb  = (const float*)d_in[1];
    const float* Wf   = (const float*)d_in[2];
    const float* bf   = (const float*)d_in[3];
    const float* Wi   = (const float*)d_in[4];
    const float* bi   = (const float*)d_in[5];
    const float* Wo   = (const float*)d_in[6];
    const float* bo   = (const float*)d_in[7];
    const float* Wc   = (const float*)d_in[8];
    const float* bc   = (const float*)d_in[9];
    const float* Wout = (const float*)d_in[10];
    const float* bout = (const float*)d_in[11];
    float* dout = (float*)d_out;
    u64*   hbuf = (u64*)d_ws;                               // [2][2048] tagged slots

    hipMemsetAsync(d_ws, 0, 2 * HID * sizeof(u64), stream); // tags <- 0 (!= any wanted step >=1)
    hipLaunchKernelGGL(lstm_persist, dim3(NCU), dim3(TPB), 0, stream,
                       seq, emb, Wf, bf, Wi, bi, Wo, bo, Wc, bc, Wout, bout,
                       dout, hbuf);
}

// Round 9
// 10400.806 us; speedup vs baseline: 1.5000x; 1.5000x over previous
//
#include <hip/hip_runtime.h>

#define NCU     256
#define TPB     512      // 8 waves, 2/SIMD
#define HID     2048
#define EMBD    512
#define HIN     2560
#define TSTEPS  4096
#define NCH     256

typedef unsigned long long u64;
typedef float f32x4 __attribute__((ext_vector_type(4)));

__device__ __forceinline__ float sig_(float x) { return 1.f / (1.f + __expf(-x)); }
__device__ __forceinline__ float th_(float x)  { float e = __expf(2.f * x); return 1.f - 2.f / (e + 1.f); }

__device__ __forceinline__ u64 ld_slot(const u64* p) {
    return __hip_atomic_load(p, __ATOMIC_RELAXED, __HIP_MEMORY_SCOPE_AGENT);
}

__device__ __forceinline__ float dot4(f32x4 a, f32x4 b) {
    return a.x * b.x + a.y * b.y + a.z * b.z + a.w * b.w;
}

extern "C" __global__ void __launch_bounds__(TPB, 2)
lstm_persist(const int* __restrict__ seq,
             const float* __restrict__ emb,
             const float* __restrict__ Wf, const float* __restrict__ bf,
             const float* __restrict__ Wi, const float* __restrict__ bi,
             const float* __restrict__ Wo, const float* __restrict__ bo,
             const float* __restrict__ Wc, const float* __restrict__ bc,
             const float* __restrict__ Wout, const float* __restrict__ bout,
             float* __restrict__ dout,
             u64* __restrict__ hbuf)        // [2][2048] tagged ping-pong: hi32=step, lo32=float bits
{
    const int b    = blockIdx.x;          // CU id == output char id
    const int tid  = threadIdx.x;
    const int wave = tid >> 6;
    const int lane = tid & 63;
    const int hidx = b * 8 + wave;        // h index owned by this wave

    __shared__ float hs[HID];             // 8 KB h broadcast
    __shared__ float wl[8][2][HID];       // 128 KB: per-wave LDS-resident weights (gates o,c)
    __shared__ float wpart[8];

    // ---- VGPR-resident weights (small enough that RA keeps them: ~100 floats) ----
    // wh0/wh1: gates f,i recurrent; cols EMBD + 4*lane + 256*j, j=0..7
    // wx*    : all 4 gates input part; cols 4*lane + 256*j, j=0..1
    // wr     : Wout[b][4*tid + {0..3}]
    f32x4 wh0[8], wh1[8], wx0[2], wx1[2], wx2[2], wx3[2], wr;
    {
        const float* b0 = Wf + (size_t)hidx * HIN;
        const float* b1 = Wi + (size_t)hidx * HIN;
        const float* b2 = Wo + (size_t)hidx * HIN;
        const float* b3 = Wc + (size_t)hidx * HIN;
        #pragma unroll
        for (int j = 0; j < 8; ++j) {
            wh0[j] = *(const f32x4*)(b0 + EMBD + 4 * lane + 256 * j);
            wh1[j] = *(const f32x4*)(b1 + EMBD + 4 * lane + 256 * j);
        }
        #pragma unroll
        for (int j = 0; j < 2; ++j) {
            wx0[j] = *(const f32x4*)(b0 + 4 * lane + 256 * j);
            wx1[j] = *(const f32x4*)(b1 + 4 * lane + 256 * j);
            wx2[j] = *(const f32x4*)(b2 + 4 * lane + 256 * j);
            wx3[j] = *(const f32x4*)(b3 + 4 * lane + 256 * j);
        }
        wr = *(const f32x4*)(Wout + (size_t)b * HID + 4 * tid);
        // ---- stage gates o,c recurrent weights into LDS (one-time, coalesced) ----
        #pragma unroll
        for (int j = 0; j < 8; ++j) {
            *(f32x4*)&wl[wave][0][4 * lane + 256 * j] =
                *(const f32x4*)(b2 + EMBD + 4 * lane + 256 * j);
            *(f32x4*)&wl[wave][1][4 * lane + 256 * j] =
                *(const f32x4*)(b3 + EMBD + 4 * lane + 256 * j);
        }
    }
    const float bias0 = bf[hidx], bias1 = bi[hidx], bias2 = bo[hidx], bias3 = bc[hidx];
    const float boutb = bout[b];

    float c = 0.f;
    int ch = seq[0];

    for (int t = 0; t <= TSTEPS; ++t) {
        // ---- x-contribution first (independent of h, off the critical path) ----
        float a0 = bias0, a1 = bias1, a2 = bias2, a3 = bias3;
        if (t < TSTEPS) {
            const float* erow = emb + (size_t)ch * EMBD;
            const f32x4 xv0 = *(const f32x4*)(erow + 4 * lane);
            const f32x4 xv1 = *(const f32x4*)(erow + 4 * lane + 256);
            a0 += dot4(wx0[0], xv0) + dot4(wx0[1], xv1);
            a1 += dot4(wx1[0], xv0) + dot4(wx1[1], xv1);
            a2 += dot4(wx2[0], xv0) + dot4(wx2[1], xv1);
            a3 += dot4(wx3[0], xv0) + dot4(wx3[1], xv1);
        }
        const int ch_next = (t + 1 < TSTEPS) ? seq[t + 1] : 0;

        // ---- stage h_t into LDS: poll tagged slots (store IS the arrival signal) ----
        if (t == 0) {
            #pragma unroll
            for (int k = 0; k < 4; ++k) hs[tid + 512 * k] = 0.f;
        } else {
            const u64* src = hbuf + (size_t)(t & 1) * HID;
            const u64* p0 = src + tid;
            const u64* p1 = src + tid + 512;
            const u64* p2 = src + tid + 1024;
            const u64* p3 = src + tid + 1536;
            const unsigned tt = (unsigned)t;
            u64 v0 = ld_slot(p0), v1 = ld_slot(p1), v2 = ld_slot(p2), v3 = ld_slot(p3);
            while (((unsigned)(v0 >> 32) != tt) | ((unsigned)(v1 >> 32) != tt) |
                   ((unsigned)(v2 >> 32) != tt) | ((unsigned)(v3 >> 32) != tt)) {
                __builtin_amdgcn_s_sleep(1);
                v0 = ld_slot(p0); v1 = ld_slot(p1); v2 = ld_slot(p2); v3 = ld_slot(p3);
            }
            hs[tid]        = __uint_as_float((unsigned)v0);
            hs[tid + 512]  = __uint_as_float((unsigned)v1);
            hs[tid + 1024] = __uint_as_float((unsigned)v2);
            hs[tid + 1536] = __uint_as_float((unsigned)v3);
        }
        __syncthreads();                                      // BAR B: hs ready

        // ---- gates (critical path): VGPR weights for f,i; LDS weights for o,c ----
        if (t < TSTEPS) {
            #pragma unroll
            for (int j = 0; j < 8; ++j) {
                const f32x4 hv = *(const f32x4*)&hs[4 * lane + 256 * j];
                const f32x4 w2 = *(const f32x4*)&wl[wave][0][4 * lane + 256 * j];
                const f32x4 w3 = *(const f32x4*)&wl[wave][1][4 * lane + 256 * j];
                a0 += dot4(wh0[j], hv);
                a1 += dot4(wh1[j], hv);
                a2 += dot4(w2, hv);
                a3 += dot4(w3, hv);
            }
            #pragma unroll
            for (int m = 32; m >= 1; m >>= 1) {               // butterfly: all lanes get sums
                a0 += __shfl_xor(a0, m, 64);
                a1 += __shfl_xor(a1, m, 64);
                a2 += __shfl_xor(a2, m, 64);
                a3 += __shfl_xor(a3, m, 64);
            }
            const float f = sig_(a0);
            const float i = sig_(a1);
            const float o = sig_(a2);
            const float g = th_(a3);
            c = f * c + i * g;                                // replicated across lanes
            const float hn = o * th_(c);
            if (lane == 0) {
                const u64 pk = ((u64)(unsigned)(t + 1) << 32) | (u64)__float_as_uint(hn);
                __hip_atomic_store(hbuf + (size_t)((t + 1) & 1) * HID + hidx, pk,
                                   __ATOMIC_RELAXED, __HIP_MEMORY_SCOPE_AGENT);
                if (t == TSTEPS - 1) {
                    dout[(size_t)TSTEPS * NCH + hidx]       = hn;   // h_last
                    dout[(size_t)TSTEPS * NCH + HID + hidx] = c;    // c_last
                }
            }
        }

        // ---- out[t-1][b] from staged h_t — after the h release, overlaps others' polls ----
        if (t > 0) {
            const f32x4 hv = *(const f32x4*)&hs[4 * tid];
            float op = dot4(wr, hv);
            #pragma unroll
            for (int m = 32; m >= 1; m >>= 1) op += __shfl_xor(op, m, 64);
            if (lane == 0) wpart[wave] = op;
        }
        __syncthreads();                                      // BAR C: wpart ready, hs reusable

        if (tid == 0 && t > 0) {
            float s = wpart[0] + wpart[1] + wpart[2] + wpart[3]
                    + wpart[4] + wpart[5] + wpart[6] + wpart[7];
            dout[(size_t)(t - 1) * NCH + b] = s + boutb;
        }
        ch = ch_next;
    }
}

extern "C" void kernel_launch(void* const* d_in, const int* in_sizes, int n_in,
                              void* d_out, int out_size, void* d_ws, size_t ws_size,
                              hipStream_t stream) {
    const int*   seq  = (const int*)d_in[0];
    const float* emb  = (const float*)d_in[1];
    const float* Wf   = (const float*)d_in[2];
    const float* bf   = (const float*)d_in[3];
    const float* Wi   = (const float*)d_in[4];
    const float* bi   = (const float*)d_in[5];
    const float* Wo   = (const float*)d_in[6];
    const float* bo   = (const float*)d_in[7];
    const float* Wc   = (const float*)d_in[8];
    const float* bc   = (const float*)d_in[9];
    const float* Wout = (const float*)d_in[10];
    const float* bout = (const float*)d_in[11];
    float* dout = (float*)d_out;
    u64*   hbuf = (u64*)d_ws;                               // [2][2048] tagged slots

    hipMemsetAsync(d_ws, 0, 2 * HID * sizeof(u64), stream); // tags <- 0 (!= any wanted step >=1)
    hipLaunchKernelGGL(lstm_persist, dim3(NCU), dim3(TPB), 0, stream,
                       seq, emb, Wf, bf, Wi, bi, Wo, bo, Wc, bc, Wout, bout,
                       dout, hbuf);
}

// Round 11
// 10360.596 us; speedup vs baseline: 1.5058x; 1.0039x over previous
//
#include <hip/hip_runtime.h>

#define NCU     256
#define TPB     512      // 8 waves, 2/SIMD
#define HID     2048
#define EMBD    512
#define HIN     2560
#define TSTEPS  4096
#define NCH     256

typedef unsigned long long u64;
typedef float f32x4 __attribute__((ext_vector_type(4)));

__device__ __forceinline__ float sig_(float x) { return 1.f / (1.f + __expf(-x)); }
__device__ __forceinline__ float th_(float x)  { float e = __expf(2.f * x); return 1.f - 2.f / (e + 1.f); }

__device__ __forceinline__ u64 ld_slot(const u64* p) {
    return __hip_atomic_load(p, __ATOMIC_RELAXED, __HIP_MEMORY_SCOPE_AGENT);
}

__device__ __forceinline__ float dot4(f32x4 a, f32x4 b) {
    return a.x * b.x + a.y * b.y + a.z * b.z + a.w * b.w;
}

// Def-point pin: value becomes asm-defined ONCE before the loop.
// Volatile asm cannot be sunk/duplicated/remat'd -> the loop cannot re-load
// the weight from memory; with pressure < 256 the RA keeps it in VGPRs.
#define PIN(v) asm volatile("" : "+v"(v))

extern "C" __global__ void __launch_bounds__(TPB, 2)
lstm_persist(const int* __restrict__ seq,
             const float* __restrict__ emb,
             const float* __restrict__ Wf, const float* __restrict__ bf,
             const float* __restrict__ Wi, const float* __restrict__ bi,
             const float* __restrict__ Wo, const float* __restrict__ bo,
             const float* __restrict__ Wc, const float* __restrict__ bc,
             const float* __restrict__ Wout, const float* __restrict__ bout,
             float* __restrict__ dout,
             u64* __restrict__ hbuf)        // [2][2048] tagged ping-pong: hi32=step, lo32=float bits
{
    const int b    = blockIdx.x;          // CU id == output char id
    const int tid  = threadIdx.x;
    const int wave = tid >> 6;
    const int lane = tid & 63;
    const int hidx = b * 8 + wave;        // h index owned by this wave

    __shared__ float hs[HID];             // 8 KB h broadcast
    __shared__ float wl[8][2][HID];       // 128 KB: per-wave LDS-resident weights (gates o,c)
    __shared__ float wpart[8];

    // ---- VGPR-resident weights (~100 floats/thread; feasible under the 256 cap) ----
    // wh0/wh1: gates f,i recurrent; cols EMBD + 4*lane + 256*j, j=0..7
    // wx*    : all 4 gates input part; cols 4*lane + 256*j, j=0..1
    // wr     : Wout[b][4*tid + {0..3}]
    f32x4 wh0[8], wh1[8], wx0[2], wx1[2], wx2[2], wx3[2], wr;
    {
        const float* b0 = Wf + (size_t)hidx * HIN;
        const float* b1 = Wi + (size_t)hidx * HIN;
        const float* b2 = Wo + (size_t)hidx * HIN;
        const float* b3 = Wc + (size_t)hidx * HIN;
        #pragma unroll
        for (int j = 0; j < 8; ++j) {
            wh0[j] = *(const f32x4*)(b0 + EMBD + 4 * lane + 256 * j);
            wh1[j] = *(const f32x4*)(b1 + EMBD + 4 * lane + 256 * j);
        }
        #pragma unroll
        for (int j = 0; j < 2; ++j) {
            wx0[j] = *(const f32x4*)(b0 + 4 * lane + 256 * j);
            wx1[j] = *(const f32x4*)(b1 + 4 * lane + 256 * j);
            wx2[j] = *(const f32x4*)(b2 + 4 * lane + 256 * j);
            wx3[j] = *(const f32x4*)(b3 + 4 * lane + 256 * j);
        }
        wr = *(const f32x4*)(Wout + (size_t)b * HID + 4 * tid);
        // ---- stage gates o,c recurrent weights into LDS (one-time, coalesced) ----
        #pragma unroll
        for (int j = 0; j < 8; ++j) {
            *(f32x4*)&wl[wave][0][4 * lane + 256 * j] =
                *(const f32x4*)(b2 + EMBD + 4 * lane + 256 * j);
            *(f32x4*)&wl[wave][1][4 * lane + 256 * j] =
                *(const f32x4*)(b3 + EMBD + 4 * lane + 256 * j);
        }
    }

    // ---- def-point pins: one-time, before the loop ----
    #pragma unroll
    for (int j = 0; j < 8; ++j) { PIN(wh0[j]); PIN(wh1[j]); }
    #pragma unroll
    for (int j = 0; j < 2; ++j) { PIN(wx0[j]); PIN(wx1[j]); PIN(wx2[j]); PIN(wx3[j]); }
    PIN(wr);

    const float bias0 = bf[hidx], bias1 = bi[hidx], bias2 = bo[hidx], bias3 = bc[hidx];
    const float boutb = bout[b];

    float c = 0.f;
    int ch = seq[0];

    for (int t = 0; t <= TSTEPS; ++t) {
        // ---- x-contribution first (independent of h, off the critical path) ----
        float a0 = bias0, a1 = bias1, a2 = bias2, a3 = bias3;
        if (t < TSTEPS) {
            const float* erow = emb + (size_t)ch * EMBD;
            const f32x4 xv0 = *(const f32x4*)(erow + 4 * lane);
            const f32x4 xv1 = *(const f32x4*)(erow + 4 * lane + 256);
            a0 += dot4(wx0[0], xv0) + dot4(wx0[1], xv1);
            a1 += dot4(wx1[0], xv0) + dot4(wx1[1], xv1);
            a2 += dot4(wx2[0], xv0) + dot4(wx2[1], xv1);
            a3 += dot4(wx3[0], xv0) + dot4(wx3[1], xv1);
        }
        const int ch_next = (t + 1 < TSTEPS) ? seq[t + 1] : 0;

        // ---- stage h_t into LDS: poll tagged slots (store IS the arrival signal) ----
        if (t == 0) {
            #pragma unroll
            for (int k = 0; k < 4; ++k) hs[tid + 512 * k] = 0.f;
        } else {
            const u64* src = hbuf + (size_t)(t & 1) * HID;
            const u64* p0 = src + tid;
            const u64* p1 = src + tid + 512;
            const u64* p2 = src + tid + 1024;
            const u64* p3 = src + tid + 1536;
            const unsigned tt = (unsigned)t;
            u64 v0 = ld_slot(p0), v1 = ld_slot(p1), v2 = ld_slot(p2), v3 = ld_slot(p3);
            while (((unsigned)(v0 >> 32) != tt) | ((unsigned)(v1 >> 32) != tt) |
                   ((unsigned)(v2 >> 32) != tt) | ((unsigned)(v3 >> 32) != tt)) {
                __builtin_amdgcn_s_sleep(1);
                v0 = ld_slot(p0); v1 = ld_slot(p1); v2 = ld_slot(p2); v3 = ld_slot(p3);
            }
            hs[tid]        = __uint_as_float((unsigned)v0);
            hs[tid + 512]  = __uint_as_float((unsigned)v1);
            hs[tid + 1024] = __uint_as_float((unsigned)v2);
            hs[tid + 1536] = __uint_as_float((unsigned)v3);
        }
        __syncthreads();                                      // BAR B: hs ready

        // ---- gates (critical path): VGPR weights for f,i; LDS weights for o,c ----
        if (t < TSTEPS) {
            #pragma unroll
            for (int j = 0; j < 8; ++j) {
                const f32x4 hv = *(const f32x4*)&hs[4 * lane + 256 * j];
                const f32x4 w2 = *(const f32x4*)&wl[wave][0][4 * lane + 256 * j];
                const f32x4 w3 = *(const f32x4*)&wl[wave][1][4 * lane + 256 * j];
                a0 += dot4(wh0[j], hv);
                a1 += dot4(wh1[j], hv);
                a2 += dot4(w2, hv);
                a3 += dot4(w3, hv);
            }
            #pragma unroll
            for (int m = 32; m >= 1; m >>= 1) {               // butterfly: all lanes get sums
                a0 += __shfl_xor(a0, m, 64);
                a1 += __shfl_xor(a1, m, 64);
                a2 += __shfl_xor(a2, m, 64);
                a3 += __shfl_xor(a3, m, 64);
            }
            const float f = sig_(a0);
            const float i = sig_(a1);
            const float o = sig_(a2);
            const float g = th_(a3);
            c = f * c + i * g;                                // replicated across lanes
            const float hn = o * th_(c);
            if (lane == 0) {
                const u64 pk = ((u64)(unsigned)(t + 1) << 32) | (u64)__float_as_uint(hn);
                __hip_atomic_store(hbuf + (size_t)((t + 1) & 1) * HID + hidx, pk,
                                   __ATOMIC_RELAXED, __HIP_MEMORY_SCOPE_AGENT);
                if (t == TSTEPS - 1) {
                    dout[(size_t)TSTEPS * NCH + hidx]       = hn;   // h_last
                    dout[(size_t)TSTEPS * NCH + HID + hidx] = c;    // c_last
                }
            }
        }

        // ---- out[t-1][b] from staged h_t — after the h release, overlaps others' polls ----
        if (t > 0) {
            const f32x4 hv = *(const f32x4*)&hs[4 * tid];
            float op = dot4(wr, hv);
            #pragma unroll
            for (int m = 32; m >= 1; m >>= 1) op += __shfl_xor(op, m, 64);
            if (lane == 0) wpart[wave] = op;
        }
        __syncthreads();                                      // BAR C: wpart ready, hs reusable

        if (tid == 0 && t > 0) {
            float s = wpart[0] + wpart[1] + wpart[2] + wpart[3]
                    + wpart[4] + wpart[5] + wpart[6] + wpart[7];
            dout[(size_t)(t - 1) * NCH + b] = s + boutb;
        }
        ch = ch_next;
    }
}

extern "C" void kernel_launch(void* const* d_in, const int* in_sizes, int n_in,
                              void* d_out, int out_size, void* d_ws, size_t ws_size,
                              hipStream_t stream) {
    const int*   seq  = (const int*)d_in[0];
    const float* emb  = (const float*)d_in[1];
    const float* Wf   = (const float*)d_in[2];
    const float* bf   = (const float*)d_in[3];
    const float* Wi   = (const float*)d_in[4];
    const float* bi   = (const float*)d_in[5];
    const float* Wo   = (const float*)d_in[6];
    const float* bo   = (const float*)d_in[7];
    const float* Wc   = (const float*)d_in[8];
    const float* bc   = (const float*)d_in[9];
    const float* Wout = (const float*)d_in[10];
    const float* bout = (const float*)d_in[11];
    float* dout = (float*)d_out;
    u64*   hbuf = (u64*)d_ws;                               // [2][2048] tagged slots

    hipMemsetAsync(d_ws, 0, 2 * HID * sizeof(u64), stream); // tags <- 0 (!= any wanted step >=1)
    hipLaunchKernelGGL(lstm_persist, dim3(NCU), dim3(TPB), 0, stream,
                       seq, emb, Wf, bf, Wi, bi, Wo, bo, Wc, bc, Wout, bout,
                       dout, hbuf);
}